// Round 7
// baseline (205.206 us; speedup 1.0000x reference)
//
#include <hip/hip_runtime.h>

#define H 4
#define DIN 128
#define DOUT 64
#define EIN 16
#define EOUT 16
#define NEG_SLOPE 0.2f

typedef unsigned short ushortT;
typedef __attribute__((ext_vector_type(4))) short bf16x4;
typedef __attribute__((ext_vector_type(8))) short bf16x8;
typedef __attribute__((ext_vector_type(4))) float f32x4;

static __device__ __forceinline__ ushortT f2bf(float f) {
  unsigned x = __float_as_uint(f);
  unsigned r = (x + 0x7FFFu + ((x >> 16) & 1u)) >> 16;   // RNE
  return (ushortT)r;
}

static __device__ __forceinline__ bf16x4 pack4(float4 v) {
  bf16x4 r;
  r[0] = (short)f2bf(v.x);
  r[1] = (short)f2bf(v.y);
  r[2] = (short)f2bf(v.z);
  r[3] = (short)f2bf(v.w);
  return r;
}

#if __has_builtin(__builtin_amdgcn_mfma_f32_16x16x16bf16_1k)
static __device__ __forceinline__ f32x4 mfma16(bf16x4 a, bf16x4 b, f32x4 c) {
  return __builtin_amdgcn_mfma_f32_16x16x16bf16_1k(a, b, c, 0, 0, 0);
}
#else
static __device__ __forceinline__ f32x4 mfma16(bf16x4 a, bf16x4 b, f32x4 c) {
  f32x4 d;
  asm volatile("v_mfma_f32_16x16x16_bf16 %0, %1, %2, %3"
               : "=v"(d) : "v"(a), "v"(b), "v"(c));
  return d;
}
#endif

static __device__ __forceinline__ f32x4 mfma32(bf16x8 a, bf16x8 b, f32x4 c) {
  return __builtin_amdgcn_mfma_f32_16x16x32_bf16(a, b, c, 0, 0, 0);
}

// ------------- MFMA node projection + fused alpha_l/alpha_r + hist ---------
__global__ __launch_bounds__(256) void k_nodeproj(const float* __restrict__ x,
                                                  const float* __restrict__ Wl,
                                                  const float* __restrict__ att_l,
                                                  const float* __restrict__ att_r,
                                                  const int* __restrict__ eidst,
                                                  int* __restrict__ cnt,
                                                  ushortT* __restrict__ xlb,
                                                  float* __restrict__ al,
                                                  float* __restrict__ ar,
                                                  int N, int E) {
  __shared__ ushortT Alds[4][4][64][8];
  int tid = threadIdx.x;
  int w = tid >> 6;          // wave = head
  int lane = tid & 63;
  int c16 = lane & 15;
  int kg = lane >> 4;
  int m0 = blockIdx.x * 64;

  for (int f = tid; f < 64 * 32; f += 256) {
    int r = f >> 5, m = f & 31;
    int gr = m0 + r;
    float4 v = make_float4(0.f, 0.f, 0.f, 0.f);
    if (gr < N) v = *(const float4*)(x + (size_t)gr * DIN + m * 4);
    int kt = m >> 3, half = (m >> 2) & 1, kq = m & 3;
    int rs = r ^ kq ^ ((kt & 1) << 2);
    *(bf16x4*)&Alds[kt][kq][rs][half * 4] = pack4(v);
  }

  bf16x8 bfr[4][4];
  const float* wbase = Wl + (size_t)(w * 64 + c16) * DIN;
#pragma unroll
  for (int ct = 0; ct < 4; ++ct) {
#pragma unroll
    for (int kt = 0; kt < 4; ++kt) {
      const float* wp = wbase + (size_t)ct * 16 * DIN + kt * 32 + kg * 4;
      float4 lo = *(const float4*)(wp);
      float4 hi = *(const float4*)(wp + 16);
      bf16x8 bb;
      bb[0] = (short)f2bf(lo.x); bb[1] = (short)f2bf(lo.y);
      bb[2] = (short)f2bf(lo.z); bb[3] = (short)f2bf(lo.w);
      bb[4] = (short)f2bf(hi.x); bb[5] = (short)f2bf(hi.y);
      bb[6] = (short)f2bf(hi.z); bb[7] = (short)f2bf(hi.w);
      bfr[ct][kt] = bb;
    }
  }

  f32x4 acc[4][4];
#pragma unroll
  for (int rt = 0; rt < 4; ++rt)
#pragma unroll
    for (int ct = 0; ct < 4; ++ct) acc[rt][ct] = (f32x4){0.f, 0.f, 0.f, 0.f};

  __syncthreads();

#pragma unroll
  for (int kt = 0; kt < 4; ++kt) {
    bf16x8 afr[4];
#pragma unroll
    for (int rt = 0; rt < 4; ++rt) {
      int rs = (rt * 16 + c16) ^ kg ^ ((kt & 1) << 2);
      afr[rt] = *(const bf16x8*)&Alds[kt][kg][rs][0];
    }
#pragma unroll
    for (int rt = 0; rt < 4; ++rt)
#pragma unroll
      for (int ct = 0; ct < 4; ++ct)
        acc[rt][ct] = mfma32(afr[rt], bfr[ct][kt], acc[rt][ct]);
  }

  float attl[4], attr[4];
#pragma unroll
  for (int ct = 0; ct < 4; ++ct) {
    attl[ct] = att_l[w * 64 + ct * 16 + c16];
    attr[ct] = att_r[w * 64 + ct * 16 + c16];
  }

#pragma unroll
  for (int rt = 0; rt < 4; ++rt) {
#pragma unroll
    for (int reg = 0; reg < 4; ++reg) {
      int r = rt * 16 + kg * 4 + reg;
      int gr = m0 + r;
      float pl = acc[rt][0][reg] * attl[0] + acc[rt][1][reg] * attl[1] +
                 acc[rt][2][reg] * attl[2] + acc[rt][3][reg] * attl[3];
      float pr = acc[rt][0][reg] * attr[0] + acc[rt][1][reg] * attr[1] +
                 acc[rt][2][reg] * attr[2] + acc[rt][3][reg] * attr[3];
#pragma unroll
      for (int off = 1; off < 16; off <<= 1) {
        pl += __shfl_xor(pl, off);
        pr += __shfl_xor(pr, off);
      }
      if (gr < N) {
        if (c16 == 0) {
          al[(size_t)gr * H + w] = pl;
          ar[(size_t)gr * H + w] = pr;
        }
#pragma unroll
        for (int ct = 0; ct < 4; ++ct)
          xlb[(size_t)gr * 256 + (ct * 16 + c16) * 4 + w] = f2bf(acc[rt][ct][reg]);
      }
    }
  }

  int total = gridDim.x * 256;
  for (int e = blockIdx.x * 256 + tid; e < E; e += total)
    atomicAdd(&cnt[eidst[e]], 1);
}

// ---------------- scans ----------------------------------------------------
__global__ __launch_bounds__(256) void k_scan1(const int* __restrict__ cnt,
                                               int* __restrict__ offs,
                                               int* __restrict__ bsum, int N) {
  __shared__ int s[256];
  int i = blockIdx.x * 256 + threadIdx.x;
  int v = (i < N) ? cnt[i] : 0;
  s[threadIdx.x] = v;
  __syncthreads();
  for (int off = 1; off < 256; off <<= 1) {
    int t = (threadIdx.x >= off) ? s[threadIdx.x - off] : 0;
    __syncthreads();
    s[threadIdx.x] += t;
    __syncthreads();
  }
  if (i < N) offs[i] = s[threadIdx.x] - v;
  if (threadIdx.x == 255) bsum[blockIdx.x] = s[255];
}

__global__ __launch_bounds__(256) void k_scan2(const int* __restrict__ bsum,
                                               int* __restrict__ boffs, int NB) {
  __shared__ int s[256];
  int v = (threadIdx.x < NB) ? bsum[threadIdx.x] : 0;
  s[threadIdx.x] = v;
  __syncthreads();
  for (int off = 1; off < 256; off <<= 1) {
    int t = (threadIdx.x >= off) ? s[threadIdx.x - off] : 0;
    __syncthreads();
    s[threadIdx.x] += t;
    __syncthreads();
  }
  if (threadIdx.x < NB) boffs[threadIdx.x] = s[threadIdx.x] - v;
}

__global__ __launch_bounds__(256) void k_scan3(int* __restrict__ offs,
                                               const int* __restrict__ boffs,
                                               int* __restrict__ cursor, int N) {
  int i = blockIdx.x * 256 + threadIdx.x;
  if (i < N) {
    int o = offs[i] + boffs[blockIdx.x];
    offs[i] = o;
    cursor[i] = o;
  }
}

// ---- MFMA edge GEMM: eout + alpha_e (coalesced, streaming only) -----------
__global__ __launch_bounds__(256) void k_edgegemm(const float* __restrict__ ea,
                                                  const float* __restrict__ We,
                                                  const float* __restrict__ att_e,
                                                  const float* __restrict__ ebias,
                                                  float* __restrict__ eout,
                                                  float* __restrict__ ae, int E) {
  __shared__ float alds[4][4][64];   // [wave][head][local edge]
  int tid = threadIdx.x;
  int w = tid >> 6;
  int lane = tid & 63;
  int col = lane & 15;
  int kg = lane >> 4;

  bf16x4 bfr0, bfr1, bfr2, bfr3, bfold;
  bfr0 = pack4(*(const float4*)(We + ((size_t)(0 * 16 + col) * 16 + kg * 4)));
  bfr1 = pack4(*(const float4*)(We + ((size_t)(1 * 16 + col) * 16 + kg * 4)));
  bfr2 = pack4(*(const float4*)(We + ((size_t)(2 * 16 + col) * 16 + kg * 4)));
  bfr3 = pack4(*(const float4*)(We + ((size_t)(3 * 16 + col) * 16 + kg * 4)));
  {
    float wf0 = 0.f, wf1 = 0.f, wf2 = 0.f, wf3 = 0.f;
    if (col < 4) {
#pragma unroll
      for (int c = 0; c < 16; ++c) {
        float av = att_e[col * 16 + c];
        float4 wv = *(const float4*)(We + (size_t)(col * 16 + c) * 16 + kg * 4);
        wf0 += wv.x * av; wf1 += wv.y * av;
        wf2 += wv.z * av; wf3 += wv.w * av;
      }
    }
    bfold = pack4(make_float4(wf0, wf1, wf2, wf3));
  }
  float bias = ebias[col];

  int ebase = blockIdx.x * 256 + w * 64;

#pragma unroll
  for (int t = 0; t < 4; ++t) {
    int tb = ebase + t * 16;
    if (tb >= E) break;
    float4 av = *(const float4*)(ea + (size_t)(tb + col) * EIN + kg * 4);
    bf16x4 afr = pack4(av);
    f32x4 z = {0.f, 0.f, 0.f, 0.f};
    f32x4 d0 = mfma16(afr, bfr0, z);
    f32x4 d1 = mfma16(afr, bfr1, z);
    f32x4 d2 = mfma16(afr, bfr2, z);
    f32x4 d3 = mfma16(afr, bfr3, z);
    f32x4 d4 = mfma16(afr, bfold, z);

#pragma unroll
    for (int reg = 0; reg < 4; ++reg) {
      float m = fmaxf(fmaxf(d0[reg], d1[reg]), fmaxf(d2[reg], d3[reg]));
      eout[(size_t)(tb + kg * 4 + reg) * EOUT + col] = fmaxf(m + bias, 0.f);
    }

    if (col < 4) {
#pragma unroll
      for (int reg = 0; reg < 4; ++reg)
        alds[w][col][t * 16 + kg * 4 + reg] = d4[reg];
    }
  }

  // coalesced alpha_e dump: lane -> edge ebase+lane, 16B
  int g = ebase + lane;
  if (g < E) {
    float4 a4 = make_float4(alds[w][0][lane], alds[w][1][lane],
                            alds[w][2][lane], alds[w][3][lane]);
    *(float4*)(ae + (size_t)g * H) = a4;
  }
}

// ---- scatter: 1 lane = 1 edge, combined 32B record {ex4, src} -------------
__global__ __launch_bounds__(256) void k_edgescatter(const int* __restrict__ ei,
                                                     const float* __restrict__ ae,
                                                     const float* __restrict__ al,
                                                     const float* __restrict__ ar,
                                                     int* __restrict__ cur,
                                                     float* __restrict__ rec, int E) {
  int e = blockIdx.x * 256 + threadIdx.x;
  if (e >= E) return;
  int sN = ei[e];
  int dN = ei[E + e];
  float4 ae4 = *(const float4*)(ae + (size_t)e * H);
  float4 a4 = *(const float4*)(al + (size_t)sN * H);
  float4 r4 = *(const float4*)(ar + (size_t)dN * H);
  float lg0 = a4.x + r4.x + ae4.x;
  float lg1 = a4.y + r4.y + ae4.y;
  float lg2 = a4.z + r4.z + ae4.z;
  float lg3 = a4.w + r4.w + ae4.w;
  lg0 = (lg0 >= 0.f) ? lg0 : NEG_SLOPE * lg0;
  lg1 = (lg1 >= 0.f) ? lg1 : NEG_SLOPE * lg1;
  lg2 = (lg2 >= 0.f) ? lg2 : NEG_SLOPE * lg2;
  lg3 = (lg3 >= 0.f) ? lg3 : NEG_SLOPE * lg3;
  int p = atomicAdd(&cur[dN], 1);
  float* rp = rec + (size_t)p * 8;
  *(float4*)rp = make_float4(__expf(lg0), __expf(lg1), __expf(lg2), __expf(lg3));
  ((int*)rp)[4] = sN;
}

// ------- aggregation: wave per node, 8B gather/edge, 4-wide unroll ---------
__global__ __launch_bounds__(256) void k_agg(const ushortT* __restrict__ xlb,
                                             const float* __restrict__ rec,
                                             const int* __restrict__ offs,
                                             const int* __restrict__ cnt,
                                             const float* __restrict__ nbias,
                                             float* __restrict__ out, int N) {
  int wv = (blockIdx.x * 256 + threadIdx.x) >> 6;
  int lane = threadIdx.x & 63;
  if (wv >= N) return;
  int deg = cnt[wv];
  int start = offs[wv];
  float acc0 = 0.f, acc1 = 0.f, acc2 = 0.f, acc3 = 0.f;
  float s0 = 0.f, s1 = 0.f, s2 = 0.f, s3 = 0.f;

  int i = 0;
  for (; i + 3 < deg; i += 4) {
    const float* r0 = rec + (size_t)(start + i) * 8;
    const float* r1 = r0 + 8;
    const float* r2 = r0 + 16;
    const float* r3 = r0 + 24;
    float4 e0 = *(const float4*)r0;
    float4 e1 = *(const float4*)r1;
    float4 e2 = *(const float4*)r2;
    float4 e3 = *(const float4*)r3;
    int sA = ((const int*)r0)[4];
    int sB = ((const int*)r1)[4];
    int sC = ((const int*)r2)[4];
    int sD = ((const int*)r3)[4];
    uint2 uA = *(const uint2*)(xlb + (size_t)sA * 256 + lane * 4);
    uint2 uB = *(const uint2*)(xlb + (size_t)sB * 256 + lane * 4);
    uint2 uC = *(const uint2*)(xlb + (size_t)sC * 256 + lane * 4);
    uint2 uD = *(const uint2*)(xlb + (size_t)sD * 256 + lane * 4);
    acc0 += e0.x * __uint_as_float(uA.x << 16) + e1.x * __uint_as_float(uB.x << 16) +
            e2.x * __uint_as_float(uC.x << 16) + e3.x * __uint_as_float(uD.x << 16);
    acc1 += e0.y * __uint_as_float(uA.x & 0xFFFF0000u) + e1.y * __uint_as_float(uB.x & 0xFFFF0000u) +
            e2.y * __uint_as_float(uC.x & 0xFFFF0000u) + e3.y * __uint_as_float(uD.x & 0xFFFF0000u);
    acc2 += e0.z * __uint_as_float(uA.y << 16) + e1.z * __uint_as_float(uB.y << 16) +
            e2.z * __uint_as_float(uC.y << 16) + e3.z * __uint_as_float(uD.y << 16);
    acc3 += e0.w * __uint_as_float(uA.y & 0xFFFF0000u) + e1.w * __uint_as_float(uB.y & 0xFFFF0000u) +
            e2.w * __uint_as_float(uC.y & 0xFFFF0000u) + e3.w * __uint_as_float(uD.y & 0xFFFF0000u);
    s0 += e0.x + e1.x + e2.x + e3.x;
    s1 += e0.y + e1.y + e2.y + e3.y;
    s2 += e0.z + e1.z + e2.z + e3.z;
    s3 += e0.w + e1.w + e2.w + e3.w;
  }
  for (; i < deg; ++i) {
    const float* r0 = rec + (size_t)(start + i) * 8;
    float4 e0 = *(const float4*)r0;
    int sA = ((const int*)r0)[4];
    uint2 uA = *(const uint2*)(xlb + (size_t)sA * 256 + lane * 4);
    acc0 += e0.x * __uint_as_float(uA.x << 16);
    acc1 += e0.y * __uint_as_float(uA.x & 0xFFFF0000u);
    acc2 += e0.z * __uint_as_float(uA.y << 16);
    acc3 += e0.w * __uint_as_float(uA.y & 0xFFFF0000u);
    s0 += e0.x; s1 += e0.y; s2 += e0.z; s3 += e0.w;
  }
  float best = acc0 / (s0 + 1e-16f);
  best = fmaxf(best, acc1 / (s1 + 1e-16f));
  best = fmaxf(best, acc2 / (s2 + 1e-16f));
  best = fmaxf(best, acc3 / (s3 + 1e-16f));
  out[(size_t)wv * DOUT + lane] = fmaxf(best + nbias[lane], 0.f);
}

// ---------------- launcher -------------------------------------------------
extern "C" void kernel_launch(void* const* d_in, const int* in_sizes, int n_in,
                              void* d_out, int out_size, void* d_ws, size_t ws_size,
                              hipStream_t stream) {
  const float* x     = (const float*)d_in[0];
  const float* ea    = (const float*)d_in[1];
  const int*   ei    = (const int*)d_in[2];
  const float* Wl    = (const float*)d_in[3];
  const float* We    = (const float*)d_in[4];
  const float* att_l = (const float*)d_in[5];
  const float* att_r = (const float*)d_in[6];
  const float* att_e = (const float*)d_in[7];
  const float* nbias = (const float*)d_in[8];
  const float* ebias = (const float*)d_in[9];

  int N = in_sizes[0] / DIN;
  int E = in_sizes[1] / EIN;

  float* out  = (float*)d_out;
  float* eout = (float*)d_out + (size_t)N * DOUT;

  char* w = (char*)d_ws;
  auto alloc = [&](size_t bytes) -> void* {
    void* p = (void*)w;
    w += (bytes + 255) & ~(size_t)255;
    return p;
  };
  ushortT* xlb = (ushortT*)alloc((size_t)N * 256 * 2);
  float* al    = (float*)alloc((size_t)N * H * 4);
  float* ar    = (float*)alloc((size_t)N * H * 4);
  int* cnt     = (int*)alloc((size_t)N * 4);
  int* offs    = (int*)alloc((size_t)N * 4);
  int* cur     = (int*)alloc((size_t)N * 4);
  int* bsum    = (int*)alloc(256 * 4);
  int* boffs   = (int*)alloc(256 * 4);
  float* ae    = (float*)alloc((size_t)E * H * 4);
  float* rec   = (float*)alloc((size_t)E * 32);

  hipMemsetAsync(cnt, 0, (size_t)N * 4, stream);

  k_nodeproj<<<(N + 63) / 64, 256, 0, stream>>>(x, Wl, att_l, att_r, ei + E, cnt,
                                                xlb, al, ar, N, E);
  k_edgegemm<<<(E + 255) / 256, 256, 0, stream>>>(ea, We, att_e, ebias, eout, ae, E);
  int NB = (N + 255) / 256;
  k_scan1<<<NB, 256, 0, stream>>>(cnt, offs, bsum, N);
  k_scan2<<<1, 256, 0, stream>>>(bsum, boffs, NB);
  k_scan3<<<NB, 256, 0, stream>>>(offs, boffs, cur, N);
  k_edgescatter<<<(E + 255) / 256, 256, 0, stream>>>(ei, ae, al, ar, cur, rec, E);
  k_agg<<<(N * 64 + 255) / 256, 256, 0, stream>>>(xlb, rec, offs, cnt,
                                                  nbias, out, N);
}